// Round 19
// baseline (267.535 us; speedup 1.0000x reference)
//
#include <hip/hip_runtime.h>
#include <hip/hip_cooperative_groups.h>
namespace cg = cooperative_groups;

// ============================ EVIDENCE LOG ============================
//  Facts: inputs fp32 time-major as shown; rows/cols int32; d_out FP32;
//    out=[out0|out1] each [Tp,n] flat; semantics = shown jnp ref (absmax
//    0.03-0.06 since R12). Sparse: gather rows[k], scatter cols[k].
//  R12 512us (global-atomic RMW amp, WRITE 282MB). R13 197us. R14 194us
//    (single-WG CSR anti-pattern). R15 149us. R16 141.8us = harness-fixed
//    ~77us (268MB ws 0xAA fills ~42us + restores) + ~65us ours across 6
//    dispatches (gaps + serialized memset->hist->scan->fill chain).
//  R17 201.7us REGRESSION: per-block edge-list build (495 x full cols scan,
//    21% occupancy) = 115us. Redundant per-block work >> dispatch overhead.
//  R18: GPUAcquisitionTimeout — infra failure, kernel never ran. Identical
//    resubmission of the R18 design:
//  THIS ROUND: ONE cooperative launch, grid.sync between phases; CSR
//    replaced by capacity-bucketed fill (cap 64, Poisson lambda=10 ->
//    overflow ~1e-30; correct spill path kept). Phase C: group-owns-county
//    register accumulation (no LDS atomics), coalesced Ct/Dt rows, native-M
//    finish. Fallback = proven R16 chain (P!=2 / small ws / coop error).
// ======================================================================

#define BS      256
#define ECAP    64
#define SPILLC  4096
#define SCAN_TH 1024

__global__ __launch_bounds__(BS)
void coop_all(const float* __restrict__ C, const float* __restrict__ D,
              const float* __restrict__ M, const float* __restrict__ cov,
              const float* __restrict__ mu, const float* __restrict__ nu,
              const float* __restrict__ ups, const float* __restrict__ zet,
              const int* __restrict__ rows, const int* __restrict__ cols,
              const float* __restrict__ Bnz, const float* __restrict__ Anz,
              const float* __restrict__ Hnz,
              float* __restrict__ Ct, float* __restrict__ Dt,
              float4* __restrict__ edges, int* __restrict__ cnt,
              int* __restrict__ spill_cnt, int* __restrict__ spill,
              float* __restrict__ out0, float* __restrict__ out1,
              int T, int NC, int NMOB, int NCOV, int NNZ, int TPn,
              int cT64, int tT64, int cTiles, int nTiles) {
    cg::grid_group grid = cg::this_grid();
    __shared__ float tile[64][65];
    __shared__ float s_a0[32][33];
    __shared__ float s_a1[32][33];

    int bid = blockIdx.x, tid = threadIdx.x;
    int nB = gridDim.x;

    // ---- phase A: transpose C,D ([T,NC]->[NC,T]) + zero cnt/spill ----
    int tTiles = cT64 * tT64;
    for (int w = bid; w < 2 * tTiles; w += nB) {
        int z = w / tTiles;
        int r = w - z * tTiles;
        int ct = r / tT64, tt = r - ct * tT64;
        const float* src = z ? D : C;
        float* dst = z ? Dt : Ct;
        int lx = tid & 63, ly = tid >> 6;           // 64 x 4
        int c0 = ct * 64, t0 = tt * 64;
        for (int rr = ly; rr < 64; rr += 4) {
            int t = t0 + rr, c = c0 + lx;
            if (t < T && c < NC) tile[rr][lx] = src[(size_t)t * NC + c];
        }
        __syncthreads();
        for (int rr = ly; rr < 64; rr += 4) {
            int c = c0 + rr, t = t0 + lx;
            if (c < NC && t < T) dst[(size_t)c * T + t] = tile[lx][rr];
        }
        __syncthreads();
    }
    for (int j = bid * BS + tid; j < NC; j += nB * BS) cnt[j] = 0;
    if (bid == 0 && tid == 0) *spill_cnt = 0;
    grid.sync();

    // ---- phase B: one-pass bucket fill (no hist/scan) ----
    for (int k = bid * BS + tid; k < NNZ; k += nB * BS) {
        int c = cols[k];
        int j = atomicAdd(&cnt[c], 1);
        if (j < ECAP)
            edges[(size_t)c * ECAP + j] =
                make_float4(__int_as_float(rows[k]), Bnz[k], Anz[k], Hnz[k]);
        else {
            int sp = atomicAdd(spill_cnt, 1);
            if (sp < SPILLC) spill[sp] = k;
        }
    }
    grid.sync();

    // ---- phase C: per (32i x 32c) tile; group-owns-county, reg accumulate ----
    for (int t = bid; t < nTiles; t += nB) {
        int bi = t / cTiles, bc = t - bi * cTiles;
        int i0 = bi * 32, c0 = bc * 32;
        int cmax = NC - c0; if (cmax > 32) cmax = 32;

        int grp = tid >> 5, li = tid & 31;
        int iA = i0 + li;
        int isafe = (iA < TPn) ? iA : (TPn - 1);    // isafe+1 <= TPn < T: safe
        for (int cl = grp; cl < 32; cl += 8) {
            float a0 = 0.f, a1 = 0.f;
            if (cl < cmax) {
                int c = c0 + cl;
                int n = cnt[c]; if (n > ECAP) n = ECAP;
                const float4* eb = edges + (size_t)c * ECAP;
                for (int j = 0; j < n; ++j) {
                    float4 E = eb[j];                // 32-lane broadcast
                    int g = __float_as_int(E.x);
                    const float* cr = Ct + (size_t)g * T;
                    const float* dr = Dt + (size_t)g * T;
                    float cs = cr[isafe] + cr[isafe + 1];   // coalesced 128B
                    float ds = dr[isafe] + dr[isafe + 1];
                    a0 += cs * E.y;
                    a1 += cs * E.w + ds * E.z;
                }
            }
            s_a0[cl][li] = a0;                       // owned: plain store
            s_a1[cl][li] = a1;
        }
        __syncthreads();

        // finish: lanes along c; cov + mob from native-layout M; store
        int lc = tid & 31, ri = tid >> 5;
        int c = c0 + lc;
        if (c < NC) {
            float cv0 = 0.f, cv1 = 0.f;
            for (int j = 0; j < NCOV; ++j) {
                float cv = cov[(size_t)j * NC + c];
                cv0 += cv * ups[j];
                cv1 += cv * zet[j];
            }
            for (int ii = ri; ii < 32; ii += 8) {
                int io = i0 + ii;
                if (io < TPn) {
                    float a0 = s_a0[lc][ii] + cv0;   // stride-33: conflict-free
                    float a1 = s_a1[lc][ii] + cv1;
                    for (int k = 0; k < NMOB; ++k) {
                        const float* mb = M + (size_t)k * T * NC;
                        float m0 = mb[(size_t)io * NC + c];
                        float m1 = mb[(size_t)(io + 1) * NC + c];
                        a0 += m0 * mu[k * 2] + m1 * mu[k * 2 + 1];
                        a1 += m0 * nu[k * 2] + m1 * nu[k * 2 + 1];
                    }
                    out0[(size_t)io * NC + c] = a0;
                    out1[(size_t)io * NC + c] = a1;
                }
            }
        }
        __syncthreads();
    }

    // ---- spill handling (empty in practice; correct path kept) ----
    int nsp = *spill_cnt;
    if (nsp > 0) {
        if (nsp > SPILLC) nsp = SPILLC;
        for (int t = bid; t < nTiles; t += nB) {
            int bi = t / cTiles, bc = t - bi * cTiles;
            int i0 = bi * 32, c0 = bc * 32;
            int cmax = NC - c0; if (cmax > 32) cmax = 32;
            if (tid < 32) {
                int io = i0 + tid;
                if (io < TPn) {
                    for (int s = 0; s < nsp; ++s) {
                        int k = spill[s];
                        int c = cols[k];
                        if (c >= c0 && c < c0 + cmax) {
                            int g = rows[k];
                            float cs = Ct[(size_t)g * T + io] + Ct[(size_t)g * T + io + 1];
                            float ds = Dt[(size_t)g * T + io] + Dt[(size_t)g * T + io + 1];
                            atomicAdd(&out0[(size_t)io * NC + c], cs * Bnz[k]);
                            atomicAdd(&out1[(size_t)io * NC + c], cs * Hnz[k] + ds * Anz[k]);
                        }
                    }
                }
            }
        }
    }
}

// ================= fallback path: proven R16 chain =================
__global__ void hist_and_transposeCD(const int* __restrict__ cols, int* __restrict__ counts,
                                     int NNZ,
                                     const float* __restrict__ C, const float* __restrict__ D,
                                     float* __restrict__ Ct, float* __restrict__ Dt,
                                     int T, int NC, int histBlocks, int cT, int tT) {
    if ((int)blockIdx.x < histBlocks) {
        int k = blockIdx.x * blockDim.x + threadIdx.x;
        if (k < NNZ) atomicAdd(&counts[cols[k]], 1);
        return;
    }
    __shared__ float tile[64][65];
    int bid = blockIdx.x - histBlocks;
    int z = bid / (cT * tT);
    int r = bid - z * cT * tT;
    int ct = r / tT, tt = r - ct * tT;
    const float* src = z ? D : C;
    float* dst = z ? Dt : Ct;
    int lx = threadIdx.x & 63, ly = threadIdx.x >> 6;
    int c0 = ct * 64, t0 = tt * 64;
    for (int rr = ly; rr < 64; rr += 4) {
        int t = t0 + rr, c = c0 + lx;
        if (t < T && c < NC) tile[rr][lx] = src[(size_t)t * NC + c];
    }
    __syncthreads();
    for (int rr = ly; rr < 64; rr += 4) {
        int c = c0 + rr, t = t0 + lx;
        if (c < NC && t < T) dst[(size_t)c * T + t] = tile[lx][rr];
    }
}

__global__ __launch_bounds__(SCAN_TH)
void csr_scan(const int* __restrict__ counts, int* __restrict__ offsets,
              int* __restrict__ cursor, int NC) {
    __shared__ int ssum[SCAN_TH];
    int t = threadIdx.x;
    int chunk = (NC + SCAN_TH - 1) / SCAN_TH;
    int beg = t * chunk, end = min(beg + chunk, NC);
    int local = 0;
    for (int j = beg; j < end; ++j) local += counts[j];
    ssum[t] = local;
    __syncthreads();
    for (int off = 1; off < SCAN_TH; off <<= 1) {
        int v = (t >= off) ? ssum[t - off] : 0;
        __syncthreads();
        ssum[t] += v;
        __syncthreads();
    }
    int run = ssum[t] - local;
    for (int j = beg; j < end; ++j) {
        offsets[j] = run;
        cursor[j]  = run;
        run += counts[j];
    }
    if (t == SCAN_TH - 1) offsets[NC] = ssum[SCAN_TH - 1];
}

__global__ void csr_fill(const int* __restrict__ rows, const int* __restrict__ cols,
                         const float* __restrict__ Bnz, const float* __restrict__ Anz,
                         const float* __restrict__ Hnz,
                         int* __restrict__ cursor, float4* __restrict__ edges, int NNZ) {
    int k = blockIdx.x * blockDim.x + threadIdx.x;
    if (k >= NNZ) return;
    int s = cols[k];
    int pos = atomicAdd(&cursor[s], 1);
    edges[pos] = make_float4(__int_as_float(rows[k]), Bnz[k], Anz[k], Hnz[k]);
}

__global__ void fused_generic(const float* __restrict__ C, const float* __restrict__ D,
                              const float* __restrict__ M, const float* __restrict__ cov,
                              const float* __restrict__ mu, const float* __restrict__ nu,
                              const float* __restrict__ ups, const float* __restrict__ zet,
                              const int* __restrict__ offsets, const float4* __restrict__ edges,
                              float* __restrict__ out0, float* __restrict__ out1,
                              int T, int NC, int NMOB, int NCOV, int P, int TPn) {
    int idx = blockIdx.x * blockDim.x + threadIdx.x;
    if (idx >= TPn * NC) return;
    int i = idx / NC;
    int c = idx - i * NC;
    float acc0 = 0.f, acc1 = 0.f;
    for (int k = 0; k < NMOB; ++k)
        for (int tau = 0; tau < P; ++tau) {
            float m = M[((size_t)k * T + i + tau) * NC + c];
            acc0 += m * mu[k * P + tau];
            acc1 += m * nu[k * P + tau];
        }
    for (int j = 0; j < NCOV; ++j) {
        float cv = cov[(size_t)j * NC + c];
        acc0 += cv * ups[j];
        acc1 += cv * zet[j];
    }
    int e0 = offsets[c], e1 = offsets[c + 1];
    for (int e = e0; e < e1; ++e) {
        float4 E = edges[e];
        int g = __float_as_int(E.x);
        float cs = 0.f, ds = 0.f;
        for (int tau = 0; tau < P; ++tau) {
            cs += C[(size_t)(i + tau) * NC + g];
            ds += D[(size_t)(i + tau) * NC + g];
        }
        acc0 += cs * E.y;
        acc1 += cs * E.w + ds * E.z;
    }
    out0[idx] = acc0;
    out1[idx] = acc1;
}

extern "C" void kernel_launch(void* const* d_in, const int* in_sizes, int n_in,
                              void* d_out, int out_size, void* d_ws, size_t ws_size,
                              hipStream_t stream) {
    const float* C    = (const float*)d_in[0];
    const float* D    = (const float*)d_in[1];
    const float* M    = (const float*)d_in[2];
    const float* cov  = (const float*)d_in[3];
    const float* Bnz  = (const float*)d_in[4];
    const float* Anz  = (const float*)d_in[5];
    const float* Hnz  = (const float*)d_in[6];
    const float* mu   = (const float*)d_in[7];
    const float* nu   = (const float*)d_in[8];
    const float* ups  = (const float*)d_in[9];
    const float* zet  = (const float*)d_in[10];
    const int*  rows  = (const int*)d_in[11];
    const int*  cols  = (const int*)d_in[12];

    int NCOV = in_sizes[9];                 // 10
    int NC   = in_sizes[3] / NCOV;          // 3144
    int T    = in_sizes[0] / NC;            // 156
    int NMOB = in_sizes[2] / in_sizes[0];   // 6
    int P    = in_sizes[7] / NMOB;          // 2
    int NNZ  = in_sizes[11];                // 31440
    int TPn  = T - P;                       // 154

    float* out0 = (float*)d_out;            // fp32
    float* out1 = out0 + (size_t)TPn * NC;

    // ws carve-up (coop): edges | Ct | Dt | cnt | spill_cnt | spill
    float4* edges   = (float4*)d_ws;
    float*  Ct      = (float*)(edges + (size_t)NC * ECAP);
    float*  Dt      = Ct + (size_t)NC * T;
    int*    cnt     = (int*)(Dt + (size_t)NC * T);
    int*    spillc  = cnt + NC;
    int*    spill   = spillc + 1;
    size_t  need    = (size_t)((char*)(spill + SPILLC) - (char*)d_ws);

    int cT64 = (NC + 63) / 64, tT64 = (T + 63) / 64;
    int cTiles = (NC + 31) / 32;            // 99
    int iTiles = (TPn + 31) / 32;           // 5
    int nTiles = iTiles * cTiles;           // 495

    bool coop_ok = false;
    if (P == 2 && ws_size >= need && nTiles <= 512) {
        void* args[] = {
            (void*)&C, (void*)&D, (void*)&M, (void*)&cov,
            (void*)&mu, (void*)&nu, (void*)&ups, (void*)&zet,
            (void*)&rows, (void*)&cols, (void*)&Bnz, (void*)&Anz, (void*)&Hnz,
            (void*)&Ct, (void*)&Dt, (void*)&edges, (void*)&cnt,
            (void*)&spillc, (void*)&spill, (void*)&out0, (void*)&out1,
            (void*)&T, (void*)&NC, (void*)&NMOB, (void*)&NCOV, (void*)&NNZ,
            (void*)&TPn, (void*)&cT64, (void*)&tT64, (void*)&cTiles, (void*)&nTiles
        };
        hipError_t err = hipLaunchCooperativeKernel(
            (const void*)coop_all, dim3(nTiles), dim3(BS), args, 0, stream);
        coop_ok = (err == hipSuccess);
    }

    if (!coop_ok) {
        // R16-proven fallback chain (also handles P != 2)
        float4* fedges   = (float4*)d_ws;
        int*    foffsets = (int*)(fedges + NNZ);
        int*    fcounts  = foffsets + (NC + 1);
        int*    fcursor  = fcounts + NC;
        float*  fCt      = (float*)(fcursor + NC);   // unused by generic
        float*  fDt      = fCt + (size_t)NC * T;
        (void)fDt;
        hipMemsetAsync(fcounts, 0, (size_t)NC * sizeof(int), stream);
        hist_and_transposeCD<<<(NNZ + BS - 1) / BS, BS, 0, stream>>>(
            cols, fcounts, NNZ, C, D, fCt, fCt, T, NC, (NNZ + BS - 1) / BS, 0, 0);
        csr_scan<<<1, SCAN_TH, 0, stream>>>(fcounts, foffsets, fcursor, NC);
        csr_fill<<<(NNZ + BS - 1) / BS, BS, 0, stream>>>(
            rows, cols, Bnz, Anz, Hnz, fcursor, fedges, NNZ);
        int n = TPn * NC;
        fused_generic<<<(n + BS - 1) / BS, BS, 0, stream>>>(
            C, D, M, cov, mu, nu, ups, zet, foffsets, fedges,
            out0, out1, T, NC, NMOB, NCOV, P, TPn);
    }
}

// Round 20
// 132.806 us; speedup vs baseline: 2.0145x; 2.0145x over previous
//
#include <hip/hip_runtime.h>

// ============================ EVIDENCE LOG ============================
//  Facts: inputs fp32 time-major as shown; rows/cols int32; d_out FP32;
//    out=[out0|out1] each [Tp,n] flat; semantics = shown jnp ref (absmax
//    0.03-0.06 since R12). Sparse: gather rows[k], scatter cols[k].
//  R12 512us (global-atomic RMW amp). R13 197. R14 194 (single-WG CSR
//    anti-pattern). R15 149. R16 141.8 BEST = ~77us harness (268MB ws-fill
//    etc) + ~65us ours over 6 dispatches. R17 202 (per-block edge build =
//    redundant work x495). R19 268: cooperative grid.sync costs ~90us —
//    device-scope fence flushes per-XCD L2s + 495-block spin; VALUBusy 2.6%.
//    Consolidation via serialization loses every time (R14/R17/R19).
//  THIS ROUND: R16 structure, CSR chain replaced by capacity buckets
//    (ECAP=64, Poisson lambda=10, overflow ~0; spill path kept correct):
//    memset -> prep(bucket-fill || transposeCD) -> sparse_wave(buckets) ->
//    final_fuse. 6 nodes -> 4, no scan, no single-WG on critical path.
// ======================================================================

#define BS      256
#define ECAP    64
#define SPILLC  4096
#define SCAN_TH 1024

// ---- dispatch 2: bucket-fill blocks || transpose-C/D blocks ----
__global__ void prep(const int* __restrict__ rows, const int* __restrict__ cols,
                     const float* __restrict__ Bnz, const float* __restrict__ Anz,
                     const float* __restrict__ Hnz,
                     const float* __restrict__ C, const float* __restrict__ D,
                     float* __restrict__ Ct, float* __restrict__ Dt,
                     float4* __restrict__ edges, int* __restrict__ cnt,
                     int* __restrict__ spill_cnt, int* __restrict__ spill,
                     int T, int NC, int NNZ, int fillBlocks, int cT64, int tT64) {
    if ((int)blockIdx.x < fillBlocks) {
        int k = blockIdx.x * BS + threadIdx.x;
        if (k < NNZ) {
            int c = cols[k];
            int j = atomicAdd(&cnt[c], 1);
            if (j < ECAP)
                edges[(size_t)c * ECAP + j] =
                    make_float4(__int_as_float(rows[k]), Bnz[k], Anz[k], Hnz[k]);
            else {
                int sp = atomicAdd(spill_cnt, 1);
                if (sp < SPILLC) spill[sp] = k;
            }
        }
        return;
    }
    __shared__ float tile[64][65];
    int bid = blockIdx.x - fillBlocks;
    int tTiles = cT64 * tT64;
    int z = bid / tTiles;
    int r = bid - z * tTiles;
    int ct = r / tT64, tt = r - ct * tT64;
    const float* src = z ? D : C;
    float* dst = z ? Dt : Ct;
    int lx = threadIdx.x & 63, ly = threadIdx.x >> 6;   // 64 x 4
    int c0 = ct * 64, t0 = tt * 64;
    for (int rr = ly; rr < 64; rr += 4) {
        int t = t0 + rr, c = c0 + lx;
        if (t < T && c < NC) tile[rr][lx] = src[(size_t)t * NC + c];
    }
    __syncthreads();
    for (int rr = ly; rr < 64; rr += 4) {
        int c = c0 + rr, t = t0 + lx;
        if (c < NC && t < T) dst[(size_t)c * T + t] = tile[lx][rr];
    }
}

// ---- dispatch 3: sparse term. wave = (county, 64 time-lanes); bucket
// edges wave-uniform; Ct/Dt coalesced; ws stores coalesced [NC, TPn]. ----
__global__ void sparse_wave(const float* __restrict__ Ct, const float* __restrict__ Dt,
                            const int* __restrict__ cnt, const float4* __restrict__ edges,
                            float* __restrict__ wsS0, float* __restrict__ wsS1,
                            int T, int TPn, int nChunks, int nWaves) {
    int gtid = blockIdx.x * blockDim.x + threadIdx.x;
    int wid = gtid >> 6, lane = threadIdx.x & 63;
    if (wid >= nWaves) return;
    int c = wid / nChunks;
    int chunk = wid - c * nChunks;
    int i = chunk * 64 + lane;
    bool valid = i < TPn;
    int isafe = valid ? i : 0;            // isafe+1 <= TPn < T: safe
    float a0 = 0.f, a1 = 0.f;
    int n = cnt[c]; if (n > ECAP) n = ECAP;
    const float4* eb = edges + (size_t)c * ECAP;
    for (int j = 0; j < n; ++j) {
        float4 E = eb[j];                 // wave-uniform broadcast
        int g = __float_as_int(E.x);
        const float* cr = Ct + (size_t)g * T;
        const float* dr = Dt + (size_t)g * T;
        float cs = cr[isafe] + cr[isafe + 1];
        float ds = dr[isafe] + dr[isafe + 1];
        a0 += cs * E.y;
        a1 += cs * E.w + ds * E.z;
    }
    if (valid) {
        wsS0[(size_t)c * TPn + i] = a0;
        wsS1[(size_t)c * TPn + i] = a1;
    }
}

// ---- dispatch 4: final fuse (R16-proven) + spill check (no-op normally) ----
#define FTI 32
#define FTC 32
__global__ void final_fuse(const float* __restrict__ wsS0, const float* __restrict__ wsS1,
                           const float* __restrict__ M,   // [NMOB, T, NC] native
                           const float* __restrict__ cov, // [NCOV, NC]
                           const float* __restrict__ mu,  // [NMOB, 2]
                           const float* __restrict__ nu,
                           const float* __restrict__ ups, const float* __restrict__ zet,
                           const float* __restrict__ Ct, const float* __restrict__ Dt,
                           const int* __restrict__ rows, const int* __restrict__ cols,
                           const float* __restrict__ Bnz, const float* __restrict__ Anz,
                           const float* __restrict__ Hnz,
                           const int* __restrict__ spill_cnt, const int* __restrict__ spill,
                           float* __restrict__ out0, float* __restrict__ out1,
                           int T, int NC, int NMOB, int NCOV, int TPn, int cTiles) {
    __shared__ float s0[FTI][FTC + 1], s1[FTI][FTC + 1];
    int bi = blockIdx.x / cTiles;
    int bc = blockIdx.x - bi * cTiles;
    int i0 = bi * FTI, c0 = bc * FTC;
    int tid = threadIdx.x;                // 256

    // phase 1: lanes along i (coalesced ws reads)
    {
        int li = tid & 31;
        int lc0 = tid >> 5;
        int i = i0 + li;
        for (int cc = lc0; cc < FTC; cc += 8) {
            int c = c0 + cc;
            float v0 = 0.f, v1 = 0.f;
            if (c < NC && i < TPn) {
                v0 = wsS0[(size_t)c * TPn + i];
                v1 = wsS1[(size_t)c * TPn + i];
            }
            s0[li][cc] = v0;
            s1[li][cc] = v1;
        }
    }
    __syncthreads();

    // phase 2: lanes along c; cov + mob native-M; coalesced stores
    int lc = tid & 31;
    int ri = tid >> 5;                    // 0..7
    int c = c0 + lc;
    if (c < NC) {
        float cv0 = 0.f, cv1 = 0.f;
        for (int j = 0; j < NCOV; ++j) {
            float cv = cov[(size_t)j * NC + c];
            cv0 += cv * ups[j];
            cv1 += cv * zet[j];
        }
        for (int ii = ri; ii < FTI; ii += 8) {
            int i = i0 + ii;
            if (i >= TPn) break;
            float a0 = s0[ii][lc] + cv0;
            float a1 = s1[ii][lc] + cv1;
            for (int k = 0; k < NMOB; ++k) {
                const float* mb = M + (size_t)k * T * NC;
                float m0 = mb[(size_t)i * NC + c];
                float m1 = mb[(size_t)(i + 1) * NC + c];
                a0 += m0 * mu[k * 2] + m1 * mu[k * 2 + 1];
                a1 += m0 * nu[k * 2] + m1 * nu[k * 2 + 1];
            }
            out0[(size_t)i * NC + c] = a0;
            out1[(size_t)i * NC + c] = a1;
        }
    }

    // spill (bucket overflow — never in practice; correct path kept)
    int nsp = *spill_cnt;
    if (nsp > 0) {
        __syncthreads();                  // ensure base stores done blockwide
        if (nsp > SPILLC) nsp = SPILLC;
        int cmax = NC - c0; if (cmax > FTC) cmax = FTC;
        if (tid < FTI) {
            int io = i0 + tid;
            if (io < TPn) {
                for (int s = 0; s < nsp; ++s) {
                    int k = spill[s];
                    int cc = cols[k];
                    if (cc >= c0 && cc < c0 + cmax) {
                        int g = rows[k];
                        float cs = Ct[(size_t)g * T + io] + Ct[(size_t)g * T + io + 1];
                        float ds = Dt[(size_t)g * T + io] + Dt[(size_t)g * T + io + 1];
                        atomicAdd(&out0[(size_t)io * NC + cc], cs * Bnz[k]);
                        atomicAdd(&out1[(size_t)io * NC + cc], cs * Hnz[k] + ds * Anz[k]);
                    }
                }
            }
        }
    }
}

// ================= fallback path (P != 2): proven CSR chain =================
__global__ void csr_hist(const int* __restrict__ cols, int* __restrict__ counts, int NNZ) {
    int k = blockIdx.x * blockDim.x + threadIdx.x;
    if (k < NNZ) atomicAdd(&counts[cols[k]], 1);
}
__global__ __launch_bounds__(SCAN_TH)
void csr_scan(const int* __restrict__ counts, int* __restrict__ offsets,
              int* __restrict__ cursor, int NC) {
    __shared__ int ssum[SCAN_TH];
    int t = threadIdx.x;
    int chunk = (NC + SCAN_TH - 1) / SCAN_TH;
    int beg = t * chunk, end = min(beg + chunk, NC);
    int local = 0;
    for (int j = beg; j < end; ++j) local += counts[j];
    ssum[t] = local;
    __syncthreads();
    for (int off = 1; off < SCAN_TH; off <<= 1) {
        int v = (t >= off) ? ssum[t - off] : 0;
        __syncthreads();
        ssum[t] += v;
        __syncthreads();
    }
    int run = ssum[t] - local;
    for (int j = beg; j < end; ++j) {
        offsets[j] = run;
        cursor[j]  = run;
        run += counts[j];
    }
    if (t == SCAN_TH - 1) offsets[NC] = ssum[SCAN_TH - 1];
}
__global__ void csr_fill(const int* __restrict__ rows, const int* __restrict__ cols,
                         const float* __restrict__ Bnz, const float* __restrict__ Anz,
                         const float* __restrict__ Hnz,
                         int* __restrict__ cursor, float4* __restrict__ edges, int NNZ) {
    int k = blockIdx.x * blockDim.x + threadIdx.x;
    if (k >= NNZ) return;
    int s = cols[k];
    int pos = atomicAdd(&cursor[s], 1);
    edges[pos] = make_float4(__int_as_float(rows[k]), Bnz[k], Anz[k], Hnz[k]);
}
__global__ void fused_generic(const float* __restrict__ C, const float* __restrict__ D,
                              const float* __restrict__ M, const float* __restrict__ cov,
                              const float* __restrict__ mu, const float* __restrict__ nu,
                              const float* __restrict__ ups, const float* __restrict__ zet,
                              const int* __restrict__ offsets, const float4* __restrict__ edges,
                              float* __restrict__ out0, float* __restrict__ out1,
                              int T, int NC, int NMOB, int NCOV, int P, int TPn) {
    int idx = blockIdx.x * blockDim.x + threadIdx.x;
    if (idx >= TPn * NC) return;
    int i = idx / NC;
    int c = idx - i * NC;
    float acc0 = 0.f, acc1 = 0.f;
    for (int k = 0; k < NMOB; ++k)
        for (int tau = 0; tau < P; ++tau) {
            float m = M[((size_t)k * T + i + tau) * NC + c];
            acc0 += m * mu[k * P + tau];
            acc1 += m * nu[k * P + tau];
        }
    for (int j = 0; j < NCOV; ++j) {
        float cv = cov[(size_t)j * NC + c];
        acc0 += cv * ups[j];
        acc1 += cv * zet[j];
    }
    int e0 = offsets[c], e1 = offsets[c + 1];
    for (int e = e0; e < e1; ++e) {
        float4 E = edges[e];
        int g = __float_as_int(E.x);
        float cs = 0.f, ds = 0.f;
        for (int tau = 0; tau < P; ++tau) {
            cs += C[(size_t)(i + tau) * NC + g];
            ds += D[(size_t)(i + tau) * NC + g];
        }
        acc0 += cs * E.y;
        acc1 += cs * E.w + ds * E.z;
    }
    out0[idx] = acc0;
    out1[idx] = acc1;
}

extern "C" void kernel_launch(void* const* d_in, const int* in_sizes, int n_in,
                              void* d_out, int out_size, void* d_ws, size_t ws_size,
                              hipStream_t stream) {
    const float* C    = (const float*)d_in[0];
    const float* D    = (const float*)d_in[1];
    const float* M    = (const float*)d_in[2];
    const float* cov  = (const float*)d_in[3];
    const float* Bnz  = (const float*)d_in[4];
    const float* Anz  = (const float*)d_in[5];
    const float* Hnz  = (const float*)d_in[6];
    const float* mu   = (const float*)d_in[7];
    const float* nu   = (const float*)d_in[8];
    const float* ups  = (const float*)d_in[9];
    const float* zet  = (const float*)d_in[10];
    const int*  rows  = (const int*)d_in[11];
    const int*  cols  = (const int*)d_in[12];

    int NCOV = in_sizes[9];                 // 10
    int NC   = in_sizes[3] / NCOV;          // 3144
    int T    = in_sizes[0] / NC;            // 156
    int NMOB = in_sizes[2] / in_sizes[0];   // 6
    int P    = in_sizes[7] / NMOB;          // 2
    int NNZ  = in_sizes[11];                // 31440
    int TPn  = T - P;                       // 154

    float* out0 = (float*)d_out;            // fp32
    float* out1 = out0 + (size_t)TPn * NC;

    // ws: edges[NC*ECAP] | cnt[NC] | spillc[1] | spill[SPILLC] | Ct | Dt | wsS0 | wsS1
    float4* edges  = (float4*)d_ws;
    int*    cnt    = (int*)(edges + (size_t)NC * ECAP);
    int*    spillc = cnt + NC;
    int*    spill  = spillc + 1;
    float*  Ct     = (float*)(spill + SPILLC);
    float*  Dt     = Ct + (size_t)NC * T;
    float*  wsS0   = Dt + (size_t)NC * T;
    float*  wsS1   = wsS0 + (size_t)NC * TPn;
    size_t  need   = (size_t)((char*)(wsS1 + (size_t)NC * TPn) - (char*)d_ws);

    if (P == 2 && ws_size >= need) {
        // node 1: zero cnt + spillc in one memset (adjacent)
        hipMemsetAsync(cnt, 0, (size_t)(NC + 1) * sizeof(int), stream);

        // node 2: bucket fill || transpose C,D
        int fillBlocks = (NNZ + BS - 1) / BS;                 // 123
        int cT64 = (NC + 63) / 64, tT64 = (T + 63) / 64;      // 50, 3
        prep<<<fillBlocks + 2 * cT64 * tT64, BS, 0, stream>>>(
            rows, cols, Bnz, Anz, Hnz, C, D, Ct, Dt,
            edges, cnt, spillc, spill, T, NC, NNZ, fillBlocks, cT64, tT64);

        // node 3: sparse term from buckets
        int nChunks = (TPn + 63) / 64;                        // 3
        int nWaves  = NC * nChunks;                           // 9432
        sparse_wave<<<(nWaves * 64 + BS - 1) / BS, BS, 0, stream>>>(
            Ct, Dt, cnt, edges, wsS0, wsS1, T, TPn, nChunks, nWaves);

        // node 4: cov + mob + store (+ spill no-op)
        int iTiles = (TPn + FTI - 1) / FTI;                   // 5
        int cTiles = (NC + FTC - 1) / FTC;                    // 99
        final_fuse<<<iTiles * cTiles, BS, 0, stream>>>(
            wsS0, wsS1, M, cov, mu, nu, ups, zet, Ct, Dt,
            rows, cols, Bnz, Anz, Hnz, spillc, spill,
            out0, out1, T, NC, NMOB, NCOV, TPn, cTiles);
    } else {
        // fallback: proven CSR chain (handles any P)
        float4* fedges   = (float4*)d_ws;
        int*    foffsets = (int*)(fedges + NNZ);
        int*    fcounts  = foffsets + (NC + 1);
        int*    fcursor  = fcounts + NC;
        hipMemsetAsync(fcounts, 0, (size_t)NC * sizeof(int), stream);
        csr_hist<<<(NNZ + BS - 1) / BS, BS, 0, stream>>>(cols, fcounts, NNZ);
        csr_scan<<<1, SCAN_TH, 0, stream>>>(fcounts, foffsets, fcursor, NC);
        csr_fill<<<(NNZ + BS - 1) / BS, BS, 0, stream>>>(
            rows, cols, Bnz, Anz, Hnz, fcursor, fedges, NNZ);
        int n = TPn * NC;
        fused_generic<<<(n + BS - 1) / BS, BS, 0, stream>>>(
            C, D, M, cov, mu, nu, ups, zet, foffsets, fedges,
            out0, out1, T, NC, NMOB, NCOV, P, TPn);
    }
}